// Round 7
// baseline (5426.067 us; speedup 1.0000x reference)
//
#include <hip/hip_runtime.h>
#include <hip/hip_bf16.h>

typedef __hip_bfloat16 bf16;
typedef short bf16x8 __attribute__((ext_vector_type(8)));
typedef float f32x4 __attribute__((ext_vector_type(4)));
typedef unsigned long long u64;
typedef unsigned int u32;

#define MFMA16(A, B, C) __builtin_amdgcn_mfma_f32_16x16x32_bf16(A, B, C, 0, 0, 0)

__device__ __forceinline__ float sigf(float x) { return 1.f / (1.f + __expf(-x)); }
__device__ __forceinline__ float tanh_fast(float x) { return 2.f / (1.f + __expf(-2.f * x)) - 1.f; }

// MALL-direct 16B load (two 8B system-relaxed atomics; bypasses L1/L2).
// Used only where cache-dedup is useless (head_k).
__device__ __forceinline__ bf16x8 ld16(const u64* p) {
  u64 lo = __hip_atomic_load(p, __ATOMIC_RELAXED, __HIP_MEMORY_SCOPE_SYSTEM);
  u64 hi = __hip_atomic_load(p + 1, __ATOMIC_RELAXED, __HIP_MEMORY_SCOPE_SYSTEM);
  union { u64 q[2]; bf16x8 v; } u;
  u.q[0] = lo; u.q[1] = hi;
  return u.v;
}

// ---------------- transpose+cast: WT[n][k] = bf16(W[k][n]) ----------------
__global__ __launch_bounds__(256) void transpose_k(const float* __restrict__ W,
                                                   bf16* __restrict__ WT,
                                                   int K, int N) {
  __shared__ bf16 tile[32][33];
  const int n0 = blockIdx.x * 32, k0 = blockIdx.y * 32;
  const int c = threadIdx.x & 31, r0 = threadIdx.x >> 5;
  for (int i = 0; i < 4; ++i) {
    int r = r0 + 8 * i;
    tile[r][c] = __float2bfloat16(W[(long)(k0 + r) * N + (n0 + c)]);
  }
  __syncthreads();
  for (int i = 0; i < 4; ++i) {
    int r = r0 + 8 * i;
    WT[(long)(n0 + r) * K + (k0 + c)] = tile[c][r];
  }
}

// bulk gather of 16 A-chunks from step matrix mat (u64*, per-t base):
// chunk (slice s=4i+q, row m) = 16B at mat + (s*64 + m)*2.
// PLAIN CACHED loads: safe under the sentinel protocol (every h line is
// first-touched only after its producer's system-scope store reached MALL,
// and buffer_inv at kernel start dropped any pre-launch stale copies).
// Lines touched are row-group-private (rows 16wv..16wv+16 of a slice are
// 256B = 2 cache lines written only by producer wave wv) -> no false sharing
// with the per-wave sub-sentinels.
__device__ __forceinline__ void gather16(const u64* __restrict__ mat, int m, int q,
                                         bf16x8* out) {
#pragma unroll
  for (int i = 0; i < 16; ++i) {
    const int s = i * 4 + q;
    out[i] = *(const bf16x8*)(mat + ((long)(s << 6) + m) * 2);
  }
}

// per-wave sentinel-plane poll: 64 lanes cover the 64 producers of this
// wave's row-group plane; whole wave spins until all are set.
__device__ __forceinline__ void pollplane(const u32* sp) {
  while (__ballot(__hip_atomic_load(sp, __ATOMIC_RELAXED,
                                    __HIP_MEMORY_SCOPE_SYSTEM) != 0) != ~0ull)
    __builtin_amdgcn_s_sleep(1);
}

// ---------------- fused 2-layer persistent LSTM, per-wave dataflow ----------
// 128 WGs x 256 thr. layer = blk>>6, w = blk&63 owns h-cols [8w,8w+8).
// NEW (r7): ZERO per-step __syncthreads. Each wave wv is an independent
// agent owning batch rows [16wv,16wv+16): it polls only its row-group's
// sentinel plane sent[t][wv][*], gathers only its rows, MFMAs, does the
// gate-exchange IN-WAVE via __shfl_xor(.,8) (gates f/o live in lane r^8),
// stages its 16 rows through a wave-private LDS strip (same-wave lgkmcnt
// ordering, no barrier), publishes them, and release-stores its own
// sub-sentinel. The 4 row-group rings never interact -> barrier stalls and
// the drain+poll serialization (wave 0 did both) disappear.
// Weights stay in LDS exactly as the proven r5 kernel.
__global__ __launch_bounds__(256, 1) void lstm2_fused_k(
    const float* __restrict__ x,  // [64][512][264] f32
    const bf16* __restrict__ WiT0, const bf16* __restrict__ WhT0,
    const float* __restrict__ bias0,
    const bf16* __restrict__ WiT1, const bf16* __restrict__ WhT1,
    const float* __restrict__ bias1,
    u64* __restrict__ h1D, u64* __restrict__ h2D,
    u32* __restrict__ sent)  // [2][512][4][64] u32, zeroed
{
  __shared__ short Wis[32 * 520];
  __shared__ short Whs[32 * 520];
  __shared__ __align__(16) bf16 hstage[64 * 8];

  const int layer = blockIdx.x >> 6;
  const int w = blockIdx.x & 63;
  const int tid = threadIdx.x;
  const int lane = tid & 63;
  const int wv = tid >> 6;
  const int q = lane >> 4;
  const int r = lane & 15;

  // Drop any stale clean lines (prior iterations / harness re-poison) from
  // this CU's L1 and this XCD's L2 so all h first-touches fetch from MALL.
  if (tid == 0) asm volatile("buffer_inv sc0 sc1" ::: "memory");

  const int K_in = layer ? 512 : 256;
  const bf16* WiT = layer ? WiT1 : WiT0;
  const bf16* WhT = layer ? WhT1 : WhT0;
  const float* bias = layer ? bias1 : bias0;
  u32* s0 = sent;                      // layer-0 sentinels [512][4][64]
  u32* s1 = sent + 512 * 4 * 64;       // layer-1 sentinels
  u64* houtD = layer ? h2D : h1D;
  u32* smy = (layer ? s1 : s0);

  // ---- stage weight slices into LDS (reused all 512 steps) ----
  for (int idx = tid; idx < 32 * 64; idx += 256) {
    const int j = idx >> 6, kc = idx & 63;
    const int zc = (j >> 3) * 512 + w * 8 + (j & 7);
    *(bf16x8*)(Whs + j * 520 + kc * 8) = *(const bf16x8*)(WhT + (long)zc * 512 + kc * 8);
  }
  const int csh = layer ? 6 : 5;
  const int cmask = (1 << csh) - 1;
  for (int idx = tid; idx < (32 << csh); idx += 256) {
    const int j = idx >> csh, kc = idx & cmask;
    const int zc = (j >> 3) * 512 + w * 8 + (j & 7);
    *(bf16x8*)(Wis + j * 520 + kc * 8) = *(const bf16x8*)(WiT + (long)zc * K_in + kc * 8);
  }

  const int m = wv * 16 + r;
  const short* wi0p = Wis + r * 520;
  const short* wi1p = Wis + (16 + r) * 520;
  const short* wh0p = Whs + r * 520;
  const short* wh1p = Whs + (16 + r) * 520;

  // eltwise (lanes r<8 of every q-group): col j = r, rows wv*16+q*4+i
  float br4[4];
#pragma unroll
  for (int g = 0; g < 4; ++g) br4[g] = bias[g * 512 + w * 8 + (r & 7)];
  float creg[4] = {0.f, 0.f, 0.f, 0.f};

  __syncthreads();  // weights staged (the ONLY barrier in the kernel)

  for (int t = 0; t < 512; ++t) {
    f32x4 acc0 = {0.f, 0.f, 0.f, 0.f};
    f32x4 acc1 = {0.f, 0.f, 0.f, 0.f};

    if (layer == 0) {
      // x-part first: independent of any producer
      bf16x8 ax[8];
      const float* row = x + ((long)m * 512 + t) * 264;
#pragma unroll
      for (int i = 0; i < 8; ++i) {
        const float4 f0 = *(const float4*)(row + i * 32 + q * 8);
        const float4 f1 = *(const float4*)(row + i * 32 + q * 8 + 4);
        union { short s[8]; bf16x8 v8; } o;
        o.s[0] = __builtin_bit_cast(short, __float2bfloat16(f0.x));
        o.s[1] = __builtin_bit_cast(short, __float2bfloat16(f0.y));
        o.s[2] = __builtin_bit_cast(short, __float2bfloat16(f0.z));
        o.s[3] = __builtin_bit_cast(short, __float2bfloat16(f0.w));
        o.s[4] = __builtin_bit_cast(short, __float2bfloat16(f1.x));
        o.s[5] = __builtin_bit_cast(short, __float2bfloat16(f1.y));
        o.s[6] = __builtin_bit_cast(short, __float2bfloat16(f1.z));
        o.s[7] = __builtin_bit_cast(short, __float2bfloat16(f1.w));
        ax[i] = o.v8;
      }
#pragma unroll
      for (int i = 0; i < 8; ++i) {
        const int kk = i * 32;
        acc0 = MFMA16(ax[i], *(const bf16x8*)(wi0p + kk + q * 8), acc0);
        acc1 = MFMA16(ax[i], *(const bf16x8*)(wi1p + kk + q * 8), acc1);
      }
      if (t > 0) {
        pollplane(s0 + ((long)(t - 1) * 4 + wv) * 64 + lane);
        bf16x8 ah[16];
        gather16(h1D + (long)(t - 1) * 8192, m, q, ah);
#pragma unroll
        for (int i = 0; i < 16; ++i) {
          const int kk = i * 32;
          acc0 = MFMA16(ah[i], *(const bf16x8*)(wh0p + kk + q * 8), acc0);
          acc1 = MFMA16(ah[i], *(const bf16x8*)(wh1p + kk + q * 8), acc1);
        }
      }
    } else {
      // x-part = h1[t]; own-layer recurrence (the critical ring) last
      pollplane(s0 + ((long)t * 4 + wv) * 64 + lane);
      bf16x8 ax[16];
      gather16(h1D + (long)t * 8192, m, q, ax);
#pragma unroll
      for (int i = 0; i < 16; ++i) {
        const int kk = i * 32;
        acc0 = MFMA16(ax[i], *(const bf16x8*)(wi0p + kk + q * 8), acc0);
        acc1 = MFMA16(ax[i], *(const bf16x8*)(wi1p + kk + q * 8), acc1);
      }
      if (t > 0) {
        pollplane(s1 + ((long)(t - 1) * 4 + wv) * 64 + lane);
        bf16x8 ah[16];
        gather16(h2D + (long)(t - 1) * 8192, m, q, ah);
#pragma unroll
        for (int i = 0; i < 16; ++i) {
          const int kk = i * 32;
          acc0 = MFMA16(ah[i], *(const bf16x8*)(wh0p + kk + q * 8), acc0);
          acc1 = MFMA16(ah[i], *(const bf16x8*)(wh1p + kk + q * 8), acc1);
        }
      }
    }

    // ---- in-wave gate exchange + eltwise ----
    // D-layout: row(b)=wv*16+q*4+i, col(n)=ntile*16+r [m89-verified].
    // acc0 = gates i (r<8) / f (r>=8); acc1 = g (r<8) / o (r>=8).
    // Partner lane^8 (same q) holds the f/o gates of the same (row, col).
    f32x4 accf, acco;
#pragma unroll
    for (int i = 0; i < 4; ++i) {
      accf[i] = __shfl_xor(acc0[i], 8, 64);
      acco[i] = __shfl_xor(acc1[i], 8, 64);
    }
    if (r < 8) {
#pragma unroll
      for (int i = 0; i < 4; ++i) {
        const float zi = acc0[i] + br4[0];
        const float zf = accf[i] + br4[1];
        const float zg = acc1[i] + br4[2];
        const float zo = acco[i] + br4[3];
        const float cnew = sigf(zf) * creg[i] + sigf(zi) * tanh_fast(zg);
        const float hnew = sigf(zo) * tanh_fast(cnew);
        creg[i] = cnew;
        hstage[(wv * 16 + q * 4 + i) * 8 + r] = __float2bfloat16(hnew);
      }
    }
    // same-wave LDS visibility (lgkmcnt-ordered, no barrier): lanes 0..15
    // read back the 16 rows this wave just staged and publish them.
    if (lane < 16) {
      const u64* src = (const u64*)(hstage + (wv * 16 + lane) * 8);
      const u64 d0 = src[0], d1 = src[1];
      u64* dst = houtD + (((long)t * 64 + w) * 64 + (wv * 16 + lane)) * 2;
      __hip_atomic_store(dst, d0, __ATOMIC_RELAXED, __HIP_MEMORY_SCOPE_SYSTEM);
      __hip_atomic_store(dst + 1, d1, __ATOMIC_RELAXED, __HIP_MEMORY_SCOPE_SYSTEM);
      if (lane == 0)  // release => vmcnt(0): this wave's data stores first
        __hip_atomic_store(smy + ((long)t * 4 + wv) * 64 + w, 1u,
                           __ATOMIC_RELEASE, __HIP_MEMORY_SCOPE_AGENT);
    }
  }
}

// ---------------- dense head: concat -> 512 -> 256 -> 64 -> sigmoid ----------
__global__ __launch_bounds__(256) void head_k(
    const u64* __restrict__ h2D,  // [512][64][64][8] bf16; reads t=511
    const float* __restrict__ x,
    const float* __restrict__ Wd0, const float* __restrict__ bd0,
    const float* __restrict__ Wd1, const float* __restrict__ bd1,
    const float* __restrict__ Wf, const float* __restrict__ bfv,
    float* __restrict__ out) {
  const int b = blockIdx.x, tid = threadIdx.x;
  __shared__ float in0[520];
  __shared__ float d0s[512];
  __shared__ float d1s[256];
  if (tid < 64) {
    const int s = tid;
    bf16x8 v = ld16(h2D + (((long)511 * 64 + s) * 64 + b) * 2);
    union { bf16x8 v8; short sh[8]; } u;
    u.v8 = v;
    for (int j = 0; j < 8; ++j)
      in0[s * 8 + j] = __bfloat162float(__builtin_bit_cast(bf16, u.sh[j]));
  }
  if (tid < 8) in0[512 + tid] = x[((long)(b * 512 + 511)) * 264 + 256 + tid];
  __syncthreads();
  for (int j = tid; j < 512; j += 256) {
    float a = bd0[j];
    for (int k = 0; k < 520; ++k) a += in0[k] * Wd0[(long)k * 512 + j];
    d0s[j] = fmaxf(a, 0.f);
  }
  __syncthreads();
  if (tid < 256) {
    const int j = tid;
    float a = bd1[j];
    for (int k = 0; k < 512; ++k) a += d0s[k] * Wd1[(long)k * 256 + j];
    d1s[j] = fmaxf(a, 0.f);
  }
  __syncthreads();
  if (tid < 64) {
    const int j = tid;
    float a = bfv[j];
    for (int k = 0; k < 256; ++k) a += d1s[k] * Wf[(long)k * 64 + j];
    out[b * 64 + j] = sigf(a);
  }
}

extern "C" void kernel_launch(void* const* d_in, const int* in_sizes, int n_in,
                              void* d_out, int out_size, void* d_ws, size_t ws_size,
                              hipStream_t stream) {
  const float* x   = (const float*)d_in[0];
  const float* Wi0 = (const float*)d_in[1];
  const float* Wh0 = (const float*)d_in[2];
  const float* b0  = (const float*)d_in[3];
  const float* Wi1 = (const float*)d_in[4];
  const float* Wh1 = (const float*)d_in[5];
  const float* b1  = (const float*)d_in[6];
  const float* Wd0 = (const float*)d_in[7];
  const float* bd0 = (const float*)d_in[8];
  const float* Wd1 = (const float*)d_in[9];
  const float* bd1 = (const float*)d_in[10];
  const float* Wf  = (const float*)d_in[11];
  const float* bf_ = (const float*)d_in[12];
  float* out = (float*)d_out;

  char* ws = (char*)d_ws;
  size_t off = 0;
  auto carve = [&](size_t bytes) {
    void* p = ws + off;
    off += (bytes + 255) & ~(size_t)255;
    return p;
  };
  u32* sent = (u32*)carve((size_t)2 * 512 * 4 * 64 * 4);  // 1 MB sub-sentinels
  const size_t zero_bytes = off;
  bf16* WiT0 = (bf16*)carve((size_t)2048 * 256 * 2);
  bf16* WhT0 = (bf16*)carve((size_t)2048 * 512 * 2);
  bf16* WiT1 = (bf16*)carve((size_t)2048 * 512 * 2);
  bf16* WhT1 = (bf16*)carve((size_t)2048 * 512 * 2);
  u64*  h1D  = (u64*)carve((size_t)512 * 64 * 64 * 16);  // 32 MB bf16 history
  u64*  h2D  = (u64*)carve((size_t)512 * 64 * 64 * 16);  // 32 MB bf16 history

  (void)hipMemsetAsync(sent, 0, zero_bytes, stream);

  transpose_k<<<dim3(2048 / 32, 256 / 32), 256, 0, stream>>>(Wi0, WiT0, 256, 2048);
  transpose_k<<<dim3(2048 / 32, 512 / 32), 256, 0, stream>>>(Wh0, WhT0, 512, 2048);
  transpose_k<<<dim3(2048 / 32, 512 / 32), 256, 0, stream>>>(Wi1, WiT1, 512, 2048);
  transpose_k<<<dim3(2048 / 32, 512 / 32), 256, 0, stream>>>(Wh1, WhT1, 512, 2048);

  lstm2_fused_k<<<128, 256, 0, stream>>>(x, WiT0, WhT0, b0, WiT1, WhT1, b1,
                                         h1D, h2D, sent);

  head_k<<<64, 256, 0, stream>>>(h2D, x, Wd0, bd0, Wd1, bd1, Wf, bf_, out);
}

// Round 8
// 4641.343 us; speedup vs baseline: 1.1691x; 1.1691x over previous
//
#include <hip/hip_runtime.h>
#include <hip/hip_bf16.h>

typedef __hip_bfloat16 bf16;
typedef short bf16x8 __attribute__((ext_vector_type(8)));
typedef float f32x4 __attribute__((ext_vector_type(4)));
typedef unsigned long long u64;
typedef unsigned int u32;

#define MFMA16(A, B, C) __builtin_amdgcn_mfma_f32_16x16x32_bf16(A, B, C, 0, 0, 0)

__device__ __forceinline__ float sigf(float x) { return 1.f / (1.f + __expf(-x)); }
__device__ __forceinline__ float tanh_fast(float x) { return 2.f / (1.f + __expf(-2.f * x)) - 1.f; }

// MALL-direct 16B load (two 8B system-relaxed atomics; bypasses L1/L2).
__device__ __forceinline__ bf16x8 ld16(const u64* p) {
  u64 lo = __hip_atomic_load(p, __ATOMIC_RELAXED, __HIP_MEMORY_SCOPE_SYSTEM);
  u64 hi = __hip_atomic_load(p + 1, __ATOMIC_RELAXED, __HIP_MEMORY_SCOPE_SYSTEM);
  union { u64 q[2]; bf16x8 v; } u;
  u.q[0] = lo; u.q[1] = hi;
  return u.v;
}

// ---------------- transpose+cast: WT[n][k] = bf16(W[k][n]) ----------------
__global__ __launch_bounds__(256) void transpose_k(const float* __restrict__ W,
                                                   bf16* __restrict__ WT,
                                                   int K, int N) {
  __shared__ bf16 tile[32][33];
  const int n0 = blockIdx.x * 32, k0 = blockIdx.y * 32;
  const int c = threadIdx.x & 31, r0 = threadIdx.x >> 5;
  for (int i = 0; i < 4; ++i) {
    int r = r0 + 8 * i;
    tile[r][c] = __float2bfloat16(W[(long)(k0 + r) * N + (n0 + c)]);
  }
  __syncthreads();
  for (int i = 0; i < 4; ++i) {
    int r = r0 + 8 * i;
    WT[(long)(n0 + r) * K + (k0 + c)] = tile[c][r];
  }
}

// speculative bulk gather of 16 A-chunks, PLAIN CACHED loads (issued before
// the sentinel poll so the L2/MALL fill overlaps the poll RT). Results may
// contain the poison pattern; fix16 repairs after the poll.
__device__ __forceinline__ void gather16(const u64* __restrict__ mat, int m, int q,
                                         bf16x8* out) {
#pragma unroll
  for (int i = 0; i < 16; ++i) {
    const int s = i * 4 + q;
    out[i] = *(const bf16x8*)(mat + ((long)(s << 6) + m) * 2);
  }
}

// post-poll repair: any chunk still showing the poison qword (0xFF.. = 4x
// bf16 NaN, unreachable for h in (-1,1)) was speculatively fetched before its
// producer published (or hit a stale-poison L2 line). The sentinel has been
// observed by now, and sentinel release-store ordered the data to MALL first,
// so ONE MALL-direct reload is guaranteed fresh — no retry loop.
__device__ __forceinline__ void fix16(const u64* __restrict__ mat, int m, int q,
                                      bf16x8* a) {
#pragma unroll
  for (int i = 0; i < 16; ++i) {
    union { bf16x8 v; u64 w[2]; } u;
    u.v = a[i];
    if (u.w[0] == ~0ull || u.w[1] == ~0ull)
      a[i] = ld16(mat + ((long)((i * 4 + q) << 6) + m) * 2);
  }
}

// ---------------- fused 2-layer persistent LSTM, sentinel dataflow ----------
// r5 skeleton (proven best): 128 WGs x 256 thr, ONE poller (wave 0) + ONE
// sentinel plane per layer, __syncthreads releases the WG.
// r8 changes inside the skeleton:
//  (a) speculative cached gather issued BEFORE the poll (fill RT overlaps
//      poll RT) + poison-fix after the poll-barrier (needs 0xFF re-poison
//      of h1D/h2D each launch).
//  (b) gate exchange via in-wave __shfl_xor(.,8) (r7-verified mapping)
//      instead of the zs LDS roundtrip: -2 barriers, -LDS traffic. Each
//      wave publishes its own 16 rows; explicit vmcnt(0) + one barrier
//      orders all publishes before wave 0's single release-sentinel.
__global__ __launch_bounds__(256, 1) void lstm2_fused_k(
    const float* __restrict__ x,  // [64][512][264] f32
    const bf16* __restrict__ WiT0, const bf16* __restrict__ WhT0,
    const float* __restrict__ bias0,
    const bf16* __restrict__ WiT1, const bf16* __restrict__ WhT1,
    const float* __restrict__ bias1,
    u64* __restrict__ h1D, u64* __restrict__ h2D,
    u32* __restrict__ sent)  // [2][512][64] u32, zeroed
{
  __shared__ short Wis[32 * 520];
  __shared__ short Whs[32 * 520];
  __shared__ __align__(16) bf16 hstage[64 * 8];

  const int layer = blockIdx.x >> 6;
  const int w = blockIdx.x & 63;
  const int tid = threadIdx.x;
  const int lane = tid & 63;
  const int wv = tid >> 6;
  const int q = lane >> 4;
  const int r = lane & 15;

  // Drop pre-launch stale clean lines from this CU's L1 / XCD's L2 so all h
  // first-touches fetch current MALL content (poison or published data).
  if (tid == 0) asm volatile("buffer_inv sc0 sc1" ::: "memory");

  const int K_in = layer ? 512 : 256;
  const bf16* WiT = layer ? WiT1 : WiT0;
  const bf16* WhT = layer ? WhT1 : WhT0;
  const float* bias = layer ? bias1 : bias0;
  u32* s0 = sent;                 // layer-0 sentinels
  u32* s1 = sent + 512 * 64;      // layer-1 sentinels
  u64* houtD = layer ? h2D : h1D;
  u32* smy = (layer ? s1 : s0);

  // ---- stage weight slices into LDS (reused all 512 steps) ----
  for (int idx = tid; idx < 32 * 64; idx += 256) {
    const int j = idx >> 6, kc = idx & 63;
    const int zc = (j >> 3) * 512 + w * 8 + (j & 7);
    *(bf16x8*)(Whs + j * 520 + kc * 8) = *(const bf16x8*)(WhT + (long)zc * 512 + kc * 8);
  }
  const int csh = layer ? 6 : 5;
  const int cmask = (1 << csh) - 1;
  for (int idx = tid; idx < (32 << csh); idx += 256) {
    const int j = idx >> csh, kc = idx & cmask;
    const int zc = (j >> 3) * 512 + w * 8 + (j & 7);
    *(bf16x8*)(Wis + j * 520 + kc * 8) = *(const bf16x8*)(WiT + (long)zc * K_in + kc * 8);
  }

  const int m = wv * 16 + r;
  const short* wi0p = Wis + r * 520;
  const short* wi1p = Wis + (16 + r) * 520;
  const short* wh0p = Whs + r * 520;
  const short* wh1p = Whs + (16 + r) * 520;

  // eltwise lanes (r<8, all q): col = w*8+r, rows wv*16+q*4+i
  float br4[4];
#pragma unroll
  for (int g = 0; g < 4; ++g) br4[g] = bias[g * 512 + w * 8 + (r & 7)];
  float creg[4] = {0.f, 0.f, 0.f, 0.f};

  __syncthreads();

  for (int t = 0; t < 512; ++t) {
    f32x4 acc0 = {0.f, 0.f, 0.f, 0.f};
    f32x4 acc1 = {0.f, 0.f, 0.f, 0.f};

    if (layer == 0) {
      // speculative gather of h1[t-1] FIRST: fill overlaps x-part + poll
      bf16x8 ah[16];
      if (t > 0) gather16(h1D + (long)(t - 1) * 8192, m, q, ah);
      bf16x8 ax[8];
      const float* row = x + ((long)m * 512 + t) * 264;
#pragma unroll
      for (int i = 0; i < 8; ++i) {
        const float4 f0 = *(const float4*)(row + i * 32 + q * 8);
        const float4 f1 = *(const float4*)(row + i * 32 + q * 8 + 4);
        union { short s[8]; bf16x8 v8; } o;
        o.s[0] = __builtin_bit_cast(short, __float2bfloat16(f0.x));
        o.s[1] = __builtin_bit_cast(short, __float2bfloat16(f0.y));
        o.s[2] = __builtin_bit_cast(short, __float2bfloat16(f0.z));
        o.s[3] = __builtin_bit_cast(short, __float2bfloat16(f0.w));
        o.s[4] = __builtin_bit_cast(short, __float2bfloat16(f1.x));
        o.s[5] = __builtin_bit_cast(short, __float2bfloat16(f1.y));
        o.s[6] = __builtin_bit_cast(short, __float2bfloat16(f1.z));
        o.s[7] = __builtin_bit_cast(short, __float2bfloat16(f1.w));
        ax[i] = o.v8;
      }
#pragma unroll
      for (int i = 0; i < 8; ++i) {
        const int kk = i * 32;
        acc0 = MFMA16(ax[i], *(const bf16x8*)(wi0p + kk + q * 8), acc0);
        acc1 = MFMA16(ax[i], *(const bf16x8*)(wi1p + kk + q * 8), acc1);
      }
      if (t > 0) {
        if (tid < 64) {
          const u32* sp = s0 + (t - 1) * 64 + tid;
          while (__ballot(__hip_atomic_load(sp, __ATOMIC_RELAXED,
                                            __HIP_MEMORY_SCOPE_SYSTEM) != 0) != ~0ull)
            __builtin_amdgcn_s_sleep(2);
        }
        __syncthreads();
        fix16(h1D + (long)(t - 1) * 8192, m, q, ah);
#pragma unroll
        for (int i = 0; i < 16; ++i) {
          const int kk = i * 32;
          acc0 = MFMA16(ah[i], *(const bf16x8*)(wh0p + kk + q * 8), acc0);
          acc1 = MFMA16(ah[i], *(const bf16x8*)(wh1p + kk + q * 8), acc1);
        }
      }
    } else {
      // speculative gather of h1[t] first; poll s0[t]; fix; Wi MFMAs with
      // the h2[t-1] spec gather in flight; poll s1[t-1]; fix; Wh MFMAs.
      bf16x8 ax[16];
      gather16(h1D + (long)t * 8192, m, q, ax);
      if (tid < 64) {
        const u32* sp = s0 + t * 64 + tid;
        while (__ballot(__hip_atomic_load(sp, __ATOMIC_RELAXED,
                                          __HIP_MEMORY_SCOPE_SYSTEM) != 0) != ~0ull)
          __builtin_amdgcn_s_sleep(2);
      }
      __syncthreads();
      fix16(h1D + (long)t * 8192, m, q, ax);
      bf16x8 ah[16];
      if (t > 0) gather16(h2D + (long)(t - 1) * 8192, m, q, ah);
#pragma unroll
      for (int i = 0; i < 16; ++i) {
        const int kk = i * 32;
        acc0 = MFMA16(ax[i], *(const bf16x8*)(wi0p + kk + q * 8), acc0);
        acc1 = MFMA16(ax[i], *(const bf16x8*)(wi1p + kk + q * 8), acc1);
      }
      if (t > 0) {
        if (tid < 64) {
          const u32* sp = s1 + (t - 1) * 64 + tid;
          while (__ballot(__hip_atomic_load(sp, __ATOMIC_RELAXED,
                                            __HIP_MEMORY_SCOPE_SYSTEM) != 0) != ~0ull)
            __builtin_amdgcn_s_sleep(2);
        }
        __syncthreads();
        fix16(h2D + (long)(t - 1) * 8192, m, q, ah);
#pragma unroll
        for (int i = 0; i < 16; ++i) {
          const int kk = i * 32;
          acc0 = MFMA16(ah[i], *(const bf16x8*)(wh0p + kk + q * 8), acc0);
          acc1 = MFMA16(ah[i], *(const bf16x8*)(wh1p + kk + q * 8), acc1);
        }
      }
    }

    // ---- in-wave gate exchange + eltwise (r7-verified mapping) ----
    // D-layout: row(b)=wv*16+q*4+i, col(n)=ntile*16+r. acc0 = i(r<8)/f(r>=8),
    // acc1 = g(r<8)/o(r>=8); partner lane^8 (same q) holds f/o for (row,col).
    f32x4 accf, acco;
#pragma unroll
    for (int i = 0; i < 4; ++i) {
      accf[i] = __shfl_xor(acc0[i], 8, 64);
      acco[i] = __shfl_xor(acc1[i], 8, 64);
    }
    if (r < 8) {
#pragma unroll
      for (int i = 0; i < 4; ++i) {
        const float zi = acc0[i] + br4[0];
        const float zf = accf[i] + br4[1];
        const float zg = acc1[i] + br4[2];
        const float zo = acco[i] + br4[3];
        const float cnew = sigf(zf) * creg[i] + sigf(zi) * tanh_fast(zg);
        const float hnew = sigf(zo) * tanh_fast(cnew);
        creg[i] = cnew;
        hstage[(wv * 16 + q * 4 + i) * 8 + r] = __float2bfloat16(hnew);
      }
    }
    asm volatile("s_waitcnt lgkmcnt(0)" ::: "memory");
    // each wave publishes its OWN 16 rows (same-wave LDS readback)
    if (lane < 16) {
      const u64* src = (const u64*)(hstage + (wv * 16 + lane) * 8);
      const u64 d0 = src[0], d1 = src[1];
      u64* dst = houtD + (((long)t * 64 + w) * 64 + (wv * 16 + lane)) * 2;
      __hip_atomic_store(dst, d0, __ATOMIC_RELAXED, __HIP_MEMORY_SCOPE_SYSTEM);
      __hip_atomic_store(dst + 1, d1, __ATOMIC_RELAXED, __HIP_MEMORY_SCOPE_SYSTEM);
    }
    // drain every wave's publish stores, then ONE sentinel (r5 skeleton)
    asm volatile("s_waitcnt vmcnt(0)" ::: "memory");
    __syncthreads();
    if (tid == 0)
      __hip_atomic_store(smy + t * 64 + w, 1u, __ATOMIC_RELEASE, __HIP_MEMORY_SCOPE_AGENT);
  }
}

// ---------------- dense head: concat -> 512 -> 256 -> 64 -> sigmoid ----------
__global__ __launch_bounds__(256) void head_k(
    const u64* __restrict__ h2D,  // [512][64][64][8] bf16; reads t=511
    const float* __restrict__ x,
    const float* __restrict__ Wd0, const float* __restrict__ bd0,
    const float* __restrict__ Wd1, const float* __restrict__ bd1,
    const float* __restrict__ Wf, const float* __restrict__ bfv,
    float* __restrict__ out) {
  const int b = blockIdx.x, tid = threadIdx.x;
  __shared__ float in0[520];
  __shared__ float d0s[512];
  __shared__ float d1s[256];
  if (tid < 64) {
    const int s = tid;
    bf16x8 v = ld16(h2D + (((long)511 * 64 + s) * 64 + b) * 2);
    union { bf16x8 v8; short sh[8]; } u;
    u.v8 = v;
    for (int j = 0; j < 8; ++j)
      in0[s * 8 + j] = __bfloat162float(__builtin_bit_cast(bf16, u.sh[j]));
  }
  if (tid < 8) in0[512 + tid] = x[((long)(b * 512 + 511)) * 264 + 256 + tid];
  __syncthreads();
  for (int j = tid; j < 512; j += 256) {
    float a = bd0[j];
    for (int k = 0; k < 520; ++k) a += in0[k] * Wd0[(long)k * 512 + j];
    d0s[j] = fmaxf(a, 0.f);
  }
  __syncthreads();
  if (tid < 256) {
    const int j = tid;
    float a = bd1[j];
    for (int k = 0; k < 512; ++k) a += d0s[k] * Wd1[(long)k * 256 + j];
    d1s[j] = fmaxf(a, 0.f);
  }
  __syncthreads();
  if (tid < 64) {
    const int j = tid;
    float a = bfv[j];
    for (int k = 0; k < 256; ++k) a += d1s[k] * Wf[(long)k * 64 + j];
    out[b * 64 + j] = sigf(a);
  }
}

extern "C" void kernel_launch(void* const* d_in, const int* in_sizes, int n_in,
                              void* d_out, int out_size, void* d_ws, size_t ws_size,
                              hipStream_t stream) {
  const float* x   = (const float*)d_in[0];
  const float* Wi0 = (const float*)d_in[1];
  const float* Wh0 = (const float*)d_in[2];
  const float* b0  = (const float*)d_in[3];
  const float* Wi1 = (const float*)d_in[4];
  const float* Wh1 = (const float*)d_in[5];
  const float* b1  = (const float*)d_in[6];
  const float* Wd0 = (const float*)d_in[7];
  const float* bd0 = (const float*)d_in[8];
  const float* Wd1 = (const float*)d_in[9];
  const float* bd1 = (const float*)d_in[10];
  const float* Wf  = (const float*)d_in[11];
  const float* bf_ = (const float*)d_in[12];
  float* out = (float*)d_out;

  char* ws = (char*)d_ws;
  size_t off = 0;
  auto carve = [&](size_t bytes) {
    void* p = ws + off;
    off += (bytes + 255) & ~(size_t)255;
    return p;
  };
  u32* sent = (u32*)carve((size_t)2 * 512 * 64 * 4);  // 256 KB sentinels
  const size_t zero_bytes = off;
  bf16* WiT0 = (bf16*)carve((size_t)2048 * 256 * 2);
  bf16* WhT0 = (bf16*)carve((size_t)2048 * 512 * 2);
  bf16* WiT1 = (bf16*)carve((size_t)2048 * 512 * 2);
  bf16* WhT1 = (bf16*)carve((size_t)2048 * 512 * 2);
  u64*  h1D  = (u64*)carve((size_t)512 * 64 * 64 * 16);  // 32 MB bf16 history
  u64*  h2D  = (u64*)carve((size_t)512 * 64 * 64 * 16);  // 32 MB (contiguous)

  (void)hipMemsetAsync(sent, 0, zero_bytes, stream);
  // re-poison h histories each launch: 0xFF = bf16 NaN = "not yet written"
  // (required by the speculative-gather + poison-fix path)
  (void)hipMemsetAsync(h1D, 0xFF, (size_t)2 * 512 * 64 * 64 * 16, stream);

  transpose_k<<<dim3(2048 / 32, 256 / 32), 256, 0, stream>>>(Wi0, WiT0, 256, 2048);
  transpose_k<<<dim3(2048 / 32, 512 / 32), 256, 0, stream>>>(Wh0, WhT0, 512, 2048);
  transpose_k<<<dim3(2048 / 32, 512 / 32), 256, 0, stream>>>(Wi1, WiT1, 512, 2048);
  transpose_k<<<dim3(2048 / 32, 512 / 32), 256, 0, stream>>>(Wh1, WhT1, 512, 2048);

  lstm2_fused_k<<<128, 256, 0, stream>>>(x, WiT0, WhT0, b0, WiT1, WhT1, b1,
                                         h1D, h2D, sent);

  head_k<<<64, 256, 0, stream>>>(h2D, x, Wd0, bd0, Wd1, bd1, Wf, bf_, out);
}

// Round 9
// 3840.725 us; speedup vs baseline: 1.4128x; 1.2085x over previous
//
#include <hip/hip_runtime.h>
#include <hip/hip_bf16.h>

typedef __hip_bfloat16 bf16;
typedef short bf16x8 __attribute__((ext_vector_type(8)));
typedef float f32x4 __attribute__((ext_vector_type(4)));
typedef unsigned long long u64;
typedef unsigned int u32;

#define MFMA16(A, B, C) __builtin_amdgcn_mfma_f32_16x16x32_bf16(A, B, C, 0, 0, 0)

__device__ __forceinline__ float sigf(float x) { return 1.f / (1.f + __expf(-x)); }
__device__ __forceinline__ float tanh_fast(float x) { return 2.f / (1.f + __expf(-2.f * x)) - 1.f; }

// MALL-direct 16B load (two 8B system-relaxed atomics; bypasses L1/L2).
// Used only where cache-dedup is useless (head_k).
__device__ __forceinline__ bf16x8 ld16(const u64* p) {
  u64 lo = __hip_atomic_load(p, __ATOMIC_RELAXED, __HIP_MEMORY_SCOPE_SYSTEM);
  u64 hi = __hip_atomic_load(p + 1, __ATOMIC_RELAXED, __HIP_MEMORY_SCOPE_SYSTEM);
  union { u64 q[2]; bf16x8 v; } u;
  u.q[0] = lo; u.q[1] = hi;
  return u.v;
}

// ---------------- transpose+cast: WT[n][k] = bf16(W[k][n]) ----------------
__global__ __launch_bounds__(256) void transpose_k(const float* __restrict__ W,
                                                   bf16* __restrict__ WT,
                                                   int K, int N) {
  __shared__ bf16 tile[32][33];
  const int n0 = blockIdx.x * 32, k0 = blockIdx.y * 32;
  const int c = threadIdx.x & 31, r0 = threadIdx.x >> 5;
  for (int i = 0; i < 4; ++i) {
    int r = r0 + 8 * i;
    tile[r][c] = __float2bfloat16(W[(long)(k0 + r) * N + (n0 + c)]);
  }
  __syncthreads();
  for (int i = 0; i < 4; ++i) {
    int r = r0 + 8 * i;
    WT[(long)(n0 + r) * K + (k0 + c)] = tile[c][r];
  }
}

// bulk gather of 16 A-chunks from step matrix mat (u64*, per-t base):
// chunk (slice s=4i+q, row m) = 16B at mat + (s*64 + m)*2.
// PLAIN CACHED loads, issued STRICTLY AFTER the sentinel poll confirmed all
// producers (r8 lesson: pre-publish cached reads install stale-poison lines
// in L2 and defeat the dedup). Safe: first-touch is post-publish, buffer_inv
// at kernel start dropped pre-launch stale lines. 16 WGs/XCD dedupe through
// their XCD L2: one MALL fill per XCD.
__device__ __forceinline__ void gather16(const u64* __restrict__ mat, int m, int q,
                                         bf16x8* out) {
#pragma unroll
  for (int i = 0; i < 16; ++i) {
    const int s = i * 4 + q;
    out[i] = *(const bf16x8*)(mat + ((long)(s << 6) + m) * 2);
  }
}

// ---------------- fused 2-layer persistent LSTM, sentinel dataflow ----------
// r5 skeleton (proven best): 128 WGs x 256 thr, layer = blk>>6, w = blk&63
// owns h-cols [8w,8w+8); ONE sentinel plane per layer; cached consumer
// gathers; system-scope publish; wave-0 release sentinel.
// r9 changes inside the skeleton (no speculation):
//  (a) layer-1 polls BOTH planes in parallel (wave 0 -> s0[t], wave 1 ->
//      s1[t-1]), one barrier, then BOTH gathers issue back-to-back so their
//      fills overlap: -1 poll RT, -1 partial fill RT per step.
//  (b) gate exchange via in-wave __shfl_xor(.,8) (verified r7/r8) instead of
//      the zs LDS roundtrip: 1 barrier instead of 2, publish distributed
//      across waves, single vmcnt(0) drain before the one release sentinel.
__global__ __launch_bounds__(256, 1) void lstm2_fused_k(
    const float* __restrict__ x,  // [64][512][264] f32
    const bf16* __restrict__ WiT0, const bf16* __restrict__ WhT0,
    const float* __restrict__ bias0,
    const bf16* __restrict__ WiT1, const bf16* __restrict__ WhT1,
    const float* __restrict__ bias1,
    u64* __restrict__ h1D, u64* __restrict__ h2D,
    u32* __restrict__ sent)  // [2][512][64] u32, zeroed
{
  __shared__ short Wis[32 * 520];
  __shared__ short Whs[32 * 520];
  __shared__ __align__(16) bf16 hstage[64 * 8];

  const int layer = blockIdx.x >> 6;
  const int w = blockIdx.x & 63;
  const int tid = threadIdx.x;
  const int lane = tid & 63;
  const int wv = tid >> 6;
  const int q = lane >> 4;
  const int r = lane & 15;

  // Drop pre-launch stale clean lines from this CU's L1 / XCD's L2 so all h
  // first-touches fetch current MALL content.
  if (tid == 0) asm volatile("buffer_inv sc0 sc1" ::: "memory");

  const int K_in = layer ? 512 : 256;
  const bf16* WiT = layer ? WiT1 : WiT0;
  const bf16* WhT = layer ? WhT1 : WhT0;
  const float* bias = layer ? bias1 : bias0;
  u32* s0 = sent;                 // layer-0 sentinels
  u32* s1 = sent + 512 * 64;      // layer-1 sentinels
  u64* houtD = layer ? h2D : h1D;
  u32* smy = (layer ? s1 : s0);

  // ---- stage weight slices into LDS (reused all 512 steps) ----
  for (int idx = tid; idx < 32 * 64; idx += 256) {
    const int j = idx >> 6, kc = idx & 63;
    const int zc = (j >> 3) * 512 + w * 8 + (j & 7);
    *(bf16x8*)(Whs + j * 520 + kc * 8) = *(const bf16x8*)(WhT + (long)zc * 512 + kc * 8);
  }
  const int csh = layer ? 6 : 5;
  const int cmask = (1 << csh) - 1;
  for (int idx = tid; idx < (32 << csh); idx += 256) {
    const int j = idx >> csh, kc = idx & cmask;
    const int zc = (j >> 3) * 512 + w * 8 + (j & 7);
    *(bf16x8*)(Wis + j * 520 + kc * 8) = *(const bf16x8*)(WiT + (long)zc * K_in + kc * 8);
  }

  const int m = wv * 16 + r;
  const short* wi0p = Wis + r * 520;
  const short* wi1p = Wis + (16 + r) * 520;
  const short* wh0p = Whs + r * 520;
  const short* wh1p = Whs + (16 + r) * 520;

  // eltwise lanes (r<8, all q): col = w*8+r, rows wv*16+q*4+i
  float br4[4];
#pragma unroll
  for (int g = 0; g < 4; ++g) br4[g] = bias[g * 512 + w * 8 + (r & 7)];
  float creg[4] = {0.f, 0.f, 0.f, 0.f};

  __syncthreads();

  for (int t = 0; t < 512; ++t) {
    f32x4 acc0 = {0.f, 0.f, 0.f, 0.f};
    f32x4 acc1 = {0.f, 0.f, 0.f, 0.f};

    if (layer == 0) {
      // x-part first: independent of any producer, overlaps others' step t-1
      bf16x8 ax[8];
      const float* row = x + ((long)m * 512 + t) * 264;
#pragma unroll
      for (int i = 0; i < 8; ++i) {
        const float4 f0 = *(const float4*)(row + i * 32 + q * 8);
        const float4 f1 = *(const float4*)(row + i * 32 + q * 8 + 4);
        union { short s[8]; bf16x8 v8; } o;
        o.s[0] = __builtin_bit_cast(short, __float2bfloat16(f0.x));
        o.s[1] = __builtin_bit_cast(short, __float2bfloat16(f0.y));
        o.s[2] = __builtin_bit_cast(short, __float2bfloat16(f0.z));
        o.s[3] = __builtin_bit_cast(short, __float2bfloat16(f0.w));
        o.s[4] = __builtin_bit_cast(short, __float2bfloat16(f1.x));
        o.s[5] = __builtin_bit_cast(short, __float2bfloat16(f1.y));
        o.s[6] = __builtin_bit_cast(short, __float2bfloat16(f1.z));
        o.s[7] = __builtin_bit_cast(short, __float2bfloat16(f1.w));
        ax[i] = o.v8;
      }
#pragma unroll
      for (int i = 0; i < 8; ++i) {
        const int kk = i * 32;
        acc0 = MFMA16(ax[i], *(const bf16x8*)(wi0p + kk + q * 8), acc0);
        acc1 = MFMA16(ax[i], *(const bf16x8*)(wi1p + kk + q * 8), acc1);
      }
      if (t > 0) {
        if (tid < 64) {  // wave 0 polls all 64 producer sentinels of h1[t-1]
          const u32* sp = s0 + (t - 1) * 64 + tid;
          while (__ballot(__hip_atomic_load(sp, __ATOMIC_RELAXED,
                                            __HIP_MEMORY_SCOPE_SYSTEM) != 0) != ~0ull)
            __builtin_amdgcn_s_sleep(2);
        }
        __syncthreads();
        bf16x8 ah[16];
        gather16(h1D + (long)(t - 1) * 8192, m, q, ah);
#pragma unroll
        for (int i = 0; i < 16; ++i) {
          const int kk = i * 32;
          acc0 = MFMA16(ah[i], *(const bf16x8*)(wh0p + kk + q * 8), acc0);
          acc1 = MFMA16(ah[i], *(const bf16x8*)(wh1p + kk + q * 8), acc1);
        }
      }
    } else {
      // r9(a): PARALLEL polls — wave 0 covers s0[t], wave 1 covers s1[t-1];
      // one barrier releases the WG with BOTH dependencies satisfied.
      if (tid < 64) {
        const u32* sp = s0 + t * 64 + tid;
        while (__ballot(__hip_atomic_load(sp, __ATOMIC_RELAXED,
                                          __HIP_MEMORY_SCOPE_SYSTEM) != 0) != ~0ull)
          __builtin_amdgcn_s_sleep(2);
      } else if (t > 0 && tid < 128) {
        const u32* sp = s1 + (t - 1) * 64 + (tid - 64);
        while (__ballot(__hip_atomic_load(sp, __ATOMIC_RELAXED,
                                          __HIP_MEMORY_SCOPE_SYSTEM) != 0) != ~0ull)
          __builtin_amdgcn_s_sleep(2);
      }
      __syncthreads();
      // both sentinels confirmed -> both gathers are non-speculative; issue
      // back-to-back so the two L2/MALL fills overlap.
      bf16x8 ax[16], ah[16];
      gather16(h1D + (long)t * 8192, m, q, ax);
      if (t > 0) gather16(h2D + (long)(t - 1) * 8192, m, q, ah);
#pragma unroll
      for (int i = 0; i < 16; ++i) {
        const int kk = i * 32;
        acc0 = MFMA16(ax[i], *(const bf16x8*)(wi0p + kk + q * 8), acc0);
        acc1 = MFMA16(ax[i], *(const bf16x8*)(wi1p + kk + q * 8), acc1);
      }
      if (t > 0) {
#pragma unroll
        for (int i = 0; i < 16; ++i) {
          const int kk = i * 32;
          acc0 = MFMA16(ah[i], *(const bf16x8*)(wh0p + kk + q * 8), acc0);
          acc1 = MFMA16(ah[i], *(const bf16x8*)(wh1p + kk + q * 8), acc1);
        }
      }
    }

    // ---- r9(b): in-wave gate exchange + eltwise (r7/r8-verified mapping) ----
    // D-layout: row(b)=wv*16+q*4+i, col(n)=ntile*16+r. acc0 = i(r<8)/f(r>=8),
    // acc1 = g(r<8)/o(r>=8); partner lane^8 (same q) holds f/o for (row,col).
    f32x4 accf, acco;
#pragma unroll
    for (int i = 0; i < 4; ++i) {
      accf[i] = __shfl_xor(acc0[i], 8, 64);
      acco[i] = __shfl_xor(acc1[i], 8, 64);
    }
    if (r < 8) {
#pragma unroll
      for (int i = 0; i < 4; ++i) {
        const float zi = acc0[i] + br4[0];
        const float zf = accf[i] + br4[1];
        const float zg = acc1[i] + br4[2];
        const float zo = acco[i] + br4[3];
        const float cnew = sigf(zf) * creg[i] + sigf(zi) * tanh_fast(zg);
        const float hnew = sigf(zo) * tanh_fast(cnew);
        creg[i] = cnew;
        hstage[(wv * 16 + q * 4 + i) * 8 + r] = __float2bfloat16(hnew);
      }
    }
    asm volatile("s_waitcnt lgkmcnt(0)" ::: "memory");
    // each wave publishes its OWN 16 rows (same-wave LDS readback)
    if (lane < 16) {
      const u64* src = (const u64*)(hstage + (wv * 16 + lane) * 8);
      const u64 d0 = src[0], d1 = src[1];
      u64* dst = houtD + (((long)t * 64 + w) * 64 + (wv * 16 + lane)) * 2;
      __hip_atomic_store(dst, d0, __ATOMIC_RELAXED, __HIP_MEMORY_SCOPE_SYSTEM);
      __hip_atomic_store(dst + 1, d1, __ATOMIC_RELAXED, __HIP_MEMORY_SCOPE_SYSTEM);
    }
    // drain every wave's publish stores, then the ONE release sentinel
    asm volatile("s_waitcnt vmcnt(0)" ::: "memory");
    __syncthreads();
    if (tid == 0)
      __hip_atomic_store(smy + t * 64 + w, 1u, __ATOMIC_RELEASE, __HIP_MEMORY_SCOPE_AGENT);
  }
}

// ---------------- dense head: concat -> 512 -> 256 -> 64 -> sigmoid ----------
__global__ __launch_bounds__(256) void head_k(
    const u64* __restrict__ h2D,  // [512][64][64][8] bf16; reads t=511
    const float* __restrict__ x,
    const float* __restrict__ Wd0, const float* __restrict__ bd0,
    const float* __restrict__ Wd1, const float* __restrict__ bd1,
    const float* __restrict__ Wf, const float* __restrict__ bfv,
    float* __restrict__ out) {
  const int b = blockIdx.x, tid = threadIdx.x;
  __shared__ float in0[520];
  __shared__ float d0s[512];
  __shared__ float d1s[256];
  if (tid < 64) {
    const int s = tid;
    bf16x8 v = ld16(h2D + (((long)511 * 64 + s) * 64 + b) * 2);
    union { bf16x8 v8; short sh[8]; } u;
    u.v8 = v;
    for (int j = 0; j < 8; ++j)
      in0[s * 8 + j] = __bfloat162float(__builtin_bit_cast(bf16, u.sh[j]));
  }
  if (tid < 8) in0[512 + tid] = x[((long)(b * 512 + 511)) * 264 + 256 + tid];
  __syncthreads();
  for (int j = tid; j < 512; j += 256) {
    float a = bd0[j];
    for (int k = 0; k < 520; ++k) a += in0[k] * Wd0[(long)k * 512 + j];
    d0s[j] = fmaxf(a, 0.f);
  }
  __syncthreads();
  if (tid < 256) {
    const int j = tid;
    float a = bd1[j];
    for (int k = 0; k < 512; ++k) a += d0s[k] * Wd1[(long)k * 256 + j];
    d1s[j] = fmaxf(a, 0.f);
  }
  __syncthreads();
  if (tid < 64) {
    const int j = tid;
    float a = bfv[j];
    for (int k = 0; k < 256; ++k) a += d1s[k] * Wf[(long)k * 64 + j];
    out[b * 64 + j] = sigf(a);
  }
}

extern "C" void kernel_launch(void* const* d_in, const int* in_sizes, int n_in,
                              void* d_out, int out_size, void* d_ws, size_t ws_size,
                              hipStream_t stream) {
  const float* x   = (const float*)d_in[0];
  const float* Wi0 = (const float*)d_in[1];
  const float* Wh0 = (const float*)d_in[2];
  const float* b0  = (const float*)d_in[3];
  const float* Wi1 = (const float*)d_in[4];
  const float* Wh1 = (const float*)d_in[5];
  const float* b1  = (const float*)d_in[6];
  const float* Wd0 = (const float*)d_in[7];
  const float* bd0 = (const float*)d_in[8];
  const float* Wd1 = (const float*)d_in[9];
  const float* bd1 = (const float*)d_in[10];
  const float* Wf  = (const float*)d_in[11];
  const float* bf_ = (const float*)d_in[12];
  float* out = (float*)d_out;

  char* ws = (char*)d_ws;
  size_t off = 0;
  auto carve = [&](size_t bytes) {
    void* p = ws + off;
    off += (bytes + 255) & ~(size_t)255;
    return p;
  };
  u32* sent = (u32*)carve((size_t)2 * 512 * 64 * 4);  // 256 KB sentinels
  const size_t zero_bytes = off;
  bf16* WiT0 = (bf16*)carve((size_t)2048 * 256 * 2);
  bf16* WhT0 = (bf16*)carve((size_t)2048 * 512 * 2);
  bf16* WiT1 = (bf16*)carve((size_t)2048 * 512 * 2);
  bf16* WhT1 = (bf16*)carve((size_t)2048 * 512 * 2);
  u64*  h1D  = (u64*)carve((size_t)512 * 64 * 64 * 16);  // 32 MB bf16 history
  u64*  h2D  = (u64*)carve((size_t)512 * 64 * 64 * 16);  // 32 MB bf16 history

  (void)hipMemsetAsync(sent, 0, zero_bytes, stream);

  transpose_k<<<dim3(2048 / 32, 256 / 32), 256, 0, stream>>>(Wi0, WiT0, 256, 2048);
  transpose_k<<<dim3(2048 / 32, 512 / 32), 256, 0, stream>>>(Wh0, WhT0, 512, 2048);
  transpose_k<<<dim3(2048 / 32, 512 / 32), 256, 0, stream>>>(Wi1, WiT1, 512, 2048);
  transpose_k<<<dim3(2048 / 32, 512 / 32), 256, 0, stream>>>(Wh1, WhT1, 512, 2048);

  lstm2_fused_k<<<128, 256, 0, stream>>>(x, WiT0, WhT0, b0, WiT1, WhT1, b1,
                                         h1D, h2D, sent);

  head_k<<<64, 256, 0, stream>>>(h2D, x, Wd0, bd0, Wd1, bd1, Wf, bf_, out);
}